// Round 8
// baseline (513.559 us; speedup 1.0000x reference)
//
#include <hip/hip_runtime.h>

#define NN 100000
#define NE 1600000
#define DD 128
#define NCB 196     // coarse buckets, 512 nodes each (dst >> 9)
#define TILE 2048   // edges per hist/scatter tile
#define NTILE 782   // ceil(NE/TILE)
#define NB 512      // mega-kernel grid (2 blocks/CU guaranteed -> co-resident)

typedef __attribute__((ext_vector_type(8))) short bf16x8;
typedef __attribute__((ext_vector_type(4))) float f32x4;
typedef __attribute__((ext_vector_type(2))) float f32x2;

union u4bf8 { uint4 u; bf16x8 v; };

__device__ __forceinline__ ushort f2bf(float f) {
    union { float f; uint i; } v; v.f = f;
    uint i = v.i;
    return (ushort)((i + 0x7fffu + ((i >> 16) & 1u)) >> 16);
}
__device__ __forceinline__ float bf2f(ushort u) {
    union { uint i; float f; } v; v.i = ((uint)u) << 16; return v.f;
}
__device__ __forceinline__ f32x2 up2(uint v) {
    union { uint i; float f; } lo, hi;
    lo.i = v << 16; hi.i = v & 0xffff0000u;
    return (f32x2){lo.f, hi.f};
}
__device__ __forceinline__ uint4 pack8(float4 a, float4 b) {
    uint4 pk;
    pk.x = (uint)f2bf(a.x) | ((uint)f2bf(a.y) << 16);
    pk.y = (uint)f2bf(a.z) | ((uint)f2bf(a.w) << 16);
    pk.z = (uint)f2bf(b.x) | ((uint)f2bf(b.y) << 16);
    pk.w = (uint)f2bf(b.z) | ((uint)f2bf(b.w) << 16);
    return pk;
}

// grid-wide barrier: device-scope arrival counter + agent fences.
// Safe because NB=512 with __launch_bounds__(256,2) guarantees 2 blocks/CU
// co-resident (512 <= 2*256); fences emit buffer_wbl2/buffer_inv on gfx950.
__device__ __forceinline__ void gbar(int* bar, int target) {
    __syncthreads();
    if (threadIdx.x == 0) {
        __threadfence();
        __hip_atomic_fetch_add(bar, 1, __ATOMIC_RELAXED, __HIP_MEMORY_SCOPE_AGENT);
        while (__hip_atomic_load(bar, __ATOMIC_RELAXED, __HIP_MEMORY_SCOPE_AGENT) < target)
            __builtin_amdgcn_s_sleep(16);
        __threadfence();
    }
    __syncthreads();
}

// one kernel for the whole graph pipeline:
//  A: xb bf16 convert + W1/2/3 bf16 convert + coarse LDS hist -> ghistP
//  B: block 0 scans 196 coarse counts -> cb, gcurP
//  C: bucketize edges by coarse dst (packed src | local_dst<<17)
//  D: blocks 0..195: per-bucket fine sort -> node-sorted csr + rowp
__global__ __launch_bounds__(256, 2) void k_mega(
        const float* __restrict__ x, uint* __restrict__ xb,
        const int* __restrict__ ei, int* __restrict__ ghistP,
        int* __restrict__ cb, int* __restrict__ gcurP,
        uint* __restrict__ buck, int* __restrict__ csr, int* __restrict__ rowp,
        const float* __restrict__ W1, const float* __restrict__ W2,
        const float* __restrict__ W3, ushort* __restrict__ Wb1,
        ushort* __restrict__ Wb2, ushort* __restrict__ Wb3,
        int* __restrict__ bar) {
    __shared__ int sA[512];
    __shared__ int sB[256];
    int t = threadIdx.x, b = blockIdx.x;

    // --- phase A ---
    // xb conversion (grid-stride over NN*16 8-elem chunks)
    for (int item = b * 256 + t; item < NN * 16; item += NB * 256) {
        int n = item >> 4, q = item & 15;
        const float* xp = x + (size_t)n * DD + q * 8;
        float4 a = *(const float4*)xp;
        float4 bb = *(const float4*)(xp + 4);
        *(uint4*)(xb + (size_t)n * 64 + q * 4) = pack8(a, bb);
    }
    // W bf16 conversion: last 24 blocks, 8 elems/thread, 49152 total
    int wid = b - (NB - 24);
    if (wid >= 0) {
        int base = (wid * 256 + t) * 8;
        const float* Ws = base < 16384 ? W1 : (base < 32768 ? W2 : W3);
        ushort* Wd = base < 16384 ? Wb1 : (base < 32768 ? Wb2 : Wb3);
        int off = base & 16383;
        float4 a = *(const float4*)(Ws + off);
        float4 bb = *(const float4*)(Ws + off + 4);
        *(uint4*)(Wd + off) = pack8(a, bb);
    }
    // coarse histogram, 2 tiles per block
    for (int rep = 0; rep < 2; ++rep) {
        int tile = b + rep * NB;
        if (tile < NTILE) {
            if (t < NCB) sA[t] = 0;
            __syncthreads();
#pragma unroll
            for (int i = 0; i < 8; ++i) {
                int e = tile * TILE + i * 256 + t;
                if (e < NE) atomicAdd(&sA[ei[NE + e] >> 9], 1);
            }
            __syncthreads();
            if (t < NCB && sA[t] > 0) atomicAdd(&ghistP[t * 16], sA[t]);
            __syncthreads();
        }
    }
    gbar(bar, NB);

    // --- phase B: block 0 scan ---
    if (b == 0) {
        if (t < NCB) sA[t] = ghistP[t * 16];
        __syncthreads();
        if (t == 0) {
            int run = 0;
            for (int i = 0; i < NCB; ++i) { int c = sA[i]; sA[i] = run; run += c; }
            sA[NCB] = run;
        }
        __syncthreads();
        if (t < NCB) { cb[t] = sA[t]; gcurP[t * 16] = sA[t]; }
        if (t == NCB) cb[NCB] = sA[NCB];
    }
    gbar(bar, 2 * NB);

    // --- phase C: bucketize, 2 tiles per block ---
    for (int rep = 0; rep < 2; ++rep) {
        int tile = b + rep * NB;
        if (tile < NTILE) {
            if (t < NCB) sA[t] = 0;
            __syncthreads();
            uint vv[8]; int bb2[8], rr[8];
#pragma unroll
            for (int i = 0; i < 8; ++i) {
                int e = tile * TILE + i * 256 + t;
                bb2[i] = -1;
                if (e < NE) {
                    int s = ei[e], d = ei[NE + e];
                    int bk = d >> 9;
                    bb2[i] = bk;
                    vv[i] = (uint)s | ((uint)(d & 511) << 17);
                    rr[i] = atomicAdd(&sA[bk], 1);
                }
            }
            __syncthreads();
            if (t < NCB && sA[t] > 0) sB[t] = atomicAdd(&gcurP[t * 16], sA[t]);
            __syncthreads();
#pragma unroll
            for (int i = 0; i < 8; ++i)
                if (bb2[i] >= 0) buck[sB[bb2[i]] + rr[i]] = vv[i];
            __syncthreads();
        }
    }
    gbar(bar, 3 * NB);

    // --- phase D: fine sort, blocks 0..195 ---
    if (b < NCB) {
        sA[t] = 0; sA[t + 256] = 0;
        __syncthreads();
        int s0 = cb[b], s1 = cb[b + 1];
        for (int i = s0 + t; i < s1; i += 256)
            atomicAdd(&sA[(buck[i] >> 17) & 511], 1);
        __syncthreads();
        int p = sA[2 * t], q = sA[2 * t + 1];
        sB[t] = p + q;
        __syncthreads();
        for (int o = 1; o < 256; o <<= 1) {
            int u = (t >= o) ? sB[t - o] : 0;
            __syncthreads();
            sB[t] += u;
            __syncthreads();
        }
        int base = sB[t] - (p + q);
        rowp[b * 512 + 2 * t]     = s0 + base;
        rowp[b * 512 + 2 * t + 1] = s0 + base + p;
        __syncthreads();
        sA[2 * t] = base;
        sA[2 * t + 1] = base + p;
        __syncthreads();
        for (int i = s0 + t; i < s1; i += 256) {
            uint v = buck[i];
            int ld = (int)((v >> 17) & 511u);
            int pos = atomicAdd(&sA[ld], 1);
            csr[s0 + pos] = (int)(v & 0x1FFFFu);
        }
    }
}

// one wave per node: agg[n] = xb[n] + sum_{j in CSR[n]} xb[j]
__global__ __launch_bounds__(256) void k_gather(const uint* __restrict__ xb,
                                                const int* __restrict__ rowp,
                                                const int* __restrict__ csr,
                                                ushort* __restrict__ agg) {
    int wave = threadIdx.x >> 6, lane = threadIdx.x & 63;
    int n = blockIdx.x * 4 + wave;
    if (n >= NN) return;
    f32x2 a = up2(xb[(size_t)n * 64 + lane]);
    int rs = rowp[n], re = rowp[n + 1];
    for (int base = rs; base < re; base += 64) {
        int m = re - base; if (m > 64) m = 64;
        int sj = (lane < m) ? csr[base + lane] : 0;
        int j = 0;
        for (; j + 8 <= m; j += 8) {
            int s0 = __shfl(sj, j),     s1 = __shfl(sj, j + 1);
            int s2 = __shfl(sj, j + 2), s3 = __shfl(sj, j + 3);
            int s4 = __shfl(sj, j + 4), s5 = __shfl(sj, j + 5);
            int s6 = __shfl(sj, j + 6), s7 = __shfl(sj, j + 7);
            uint v0 = xb[(size_t)s0 * 64 + lane], v1 = xb[(size_t)s1 * 64 + lane];
            uint v2 = xb[(size_t)s2 * 64 + lane], v3 = xb[(size_t)s3 * 64 + lane];
            uint v4 = xb[(size_t)s4 * 64 + lane], v5 = xb[(size_t)s5 * 64 + lane];
            uint v6 = xb[(size_t)s6 * 64 + lane], v7 = xb[(size_t)s7 * 64 + lane];
            a += up2(v0) + up2(v1) + up2(v2) + up2(v3)
               + up2(v4) + up2(v5) + up2(v6) + up2(v7);
        }
        for (; j < m; ++j) {
            int s = __shfl(sj, j);
            a += up2(xb[(size_t)s * 64 + lane]);
        }
    }
    uint pk = (uint)f2bf(a.x) | ((uint)f2bf(a.y) << 16);
    ((uint*)(agg + (size_t)n * DD))[lane] = pk;
}

// MODE 1: A = bf16 agg, no pre-transform, bias, bf16 out, emit colstats
// MODE 2: A = bf16 t1,  in-block BN from statsIn/g/be + relu, bias, bf16 out, stats
// MODE 3: A = bf16 t2,  in-block BN + relu, no bias, relu output, fp32 out, no stats
template <int MODE>
__global__ __launch_bounds__(256) void k_gemm(const ushort* __restrict__ Ain,
                                              const ushort* __restrict__ Wb,
                                              const float* __restrict__ bias,
                                              const float* __restrict__ statsIn,
                                              const float* __restrict__ g,
                                              const float* __restrict__ be,
                                              void* __restrict__ Outv,
                                              float* __restrict__ statsOut) {
    __shared__ ushort lw[DD * 136];
    __shared__ float red[2][4][DD];
    __shared__ float lac[2 * DD];

    int tid = threadIdx.x;
    // stage pre-converted bf16 W (32 KB) into LDS
#pragma unroll
    for (int it = 0; it < 4; ++it) {
        int idx = (it * 256 + tid) * 16;
        int r = idx >> 7, k = idx & 127;
        uint4 v0 = *(const uint4*)(Wb + idx);
        uint4 v1 = *(const uint4*)(Wb + idx + 8);
        *(uint4*)&lw[r * 136 + k] = v0;
        *(uint4*)&lw[r * 136 + k + 8] = v1;
    }
    if constexpr (MODE != 1) {
        if (tid < DD) {
            float inv = 1.f / (float)NN;
            float mean = statsIn[tid] * inv;
            float var = statsIn[DD + tid] * inv - mean * mean;
            float a = g[tid] * rsqrtf(var + 1e-5f);
            lac[tid] = a;
            lac[DD + tid] = be[tid] - mean * a;
        }
    }
    __syncthreads();

    int wave = tid >> 6, lane = tid & 63;
    int lm = lane & 15, quad = lane >> 4;
    int row0 = blockIdx.x * 64 + wave * 16;
    int arow = row0 + lm;
    int ar = (arow < NN) ? arow : 0;

    bf16x8 afrag[4];
#pragma unroll
    for (int kb = 0; kb < 4; ++kb) {
        int k0 = kb * 32 + quad * 8;
        const ushort* ap = Ain + (size_t)ar * DD + k0;
        u4bf8 u; u.u = *(const uint4*)ap;
        if constexpr (MODE == 1) {
            afrag[kb] = u.v;
        } else {
            uint pk[4] = {u.u.x, u.u.y, u.u.z, u.u.w};
            bf16x8 af;
#pragma unroll
            for (int jj = 0; jj < 4; ++jj) {
                int k = k0 + jj * 2;
                f32x2 v = up2(pk[jj]);
                float v0 = fmaxf(fmaf(v.x, lac[k], lac[DD + k]), 0.f);
                float v1 = fmaxf(fmaf(v.y, lac[k + 1], lac[DD + k + 1]), 0.f);
                af[jj * 2]     = (short)f2bf(v0);
                af[jj * 2 + 1] = (short)f2bf(v1);
            }
            afrag[kb] = af;
        }
    }

    f32x4 acc[8];
#pragma unroll
    for (int nt = 0; nt < 8; ++nt) {
        float bv = (MODE == 3) ? 0.f : bias[nt * 16 + lm];
        acc[nt] = (f32x4){bv, bv, bv, bv};
    }

#pragma unroll
    for (int kb = 0; kb < 4; ++kb) {
#pragma unroll
        for (int nt = 0; nt < 8; ++nt) {
            bf16x8 bfrag = *(const bf16x8*)&lw[(nt * 16 + lm) * 136 + kb * 32 + quad * 8];
            acc[nt] = __builtin_amdgcn_mfma_f32_16x16x32_bf16(afrag[kb], bfrag, acc[nt], 0, 0, 0);
        }
    }

    ushort* Out16 = (ushort*)Outv;
    float* Out32 = (float*)Outv;
    float csum[8], csq[8];
#pragma unroll
    for (int nt = 0; nt < 8; ++nt) {
        int col = nt * 16 + lm;
        float s = 0.f, q = 0.f;
#pragma unroll
        for (int r = 0; r < 4; ++r) {
            int row = row0 + quad * 4 + r;
            float v = acc[nt][r];
            if (MODE == 3) v = fmaxf(v, 0.f);
            if (row < NN) {
                if constexpr (MODE == 3) Out32[(size_t)row * DD + col] = v;
                else Out16[(size_t)row * DD + col] = f2bf(v);
                s += v;
                q += v * v;
            }
        }
        csum[nt] = s; csq[nt] = q;
    }

    if constexpr (MODE != 3) {
#pragma unroll
        for (int nt = 0; nt < 8; ++nt) {
            float s = csum[nt], q = csq[nt];
            s += __shfl_down(s, 16, 64); q += __shfl_down(q, 16, 64);
            s += __shfl_down(s, 32, 64); q += __shfl_down(q, 32, 64);
            if (quad == 0) {
                red[0][wave][nt * 16 + lm] = s;
                red[1][wave][nt * 16 + lm] = q;
            }
        }
        __syncthreads();
        if (tid < DD) {
            float S = red[0][0][tid] + red[0][1][tid] + red[0][2][tid] + red[0][3][tid];
            float Q = red[1][0][tid] + red[1][1][tid] + red[1][2][tid] + red[1][3][tid];
            atomicAdd(&statsOut[tid], S);
            atomicAdd(&statsOut[DD + tid], Q);
        }
    }
}

extern "C" void kernel_launch(void* const* d_in, const int* in_sizes, int n_in,
                              void* d_out, int out_size, void* d_ws, size_t ws_size,
                              hipStream_t stream) {
    const float* x   = (const float*)d_in[0];
    const int* ei    = (const int*)d_in[1];
    const float* W1  = (const float*)d_in[2];
    const float* b1  = (const float*)d_in[3];
    const float* g1  = (const float*)d_in[4];
    const float* be1 = (const float*)d_in[5];
    const float* W2  = (const float*)d_in[6];
    const float* b2  = (const float*)d_in[7];
    const float* g2  = (const float*)d_in[8];
    const float* be2 = (const float*)d_in[9];
    const float* W3  = (const float*)d_in[10];

    // ws: bar[16] | stats[512] | ghistP[3136]   <- zeroed by one memset
    //   | cb[200] | gcurP[3136] | rowp[NCB*512+4]
    //   | Wb1/2/3 bf16[16384 each] | buck u32[NE] | csr i32[NE]
    //   | agg bf16[NN*DD] (reused as t2)        ~39 MB
    int* bar     = (int*)d_ws;
    float* stats = (float*)d_ws + 16;
    int* ghistP  = (int*)d_ws + 16 + 512;
    int* cb      = ghistP + 3136;
    int* gcurP   = cb + 200;
    int* rowp    = gcurP + 3136;
    ushort* Wb1  = (ushort*)(rowp + NCB * 512 + 4);
    ushort* Wb2  = Wb1 + 16384;
    ushort* Wb3  = Wb2 + 16384;
    uint* buck   = (uint*)(Wb3 + 16384);
    int* csr     = (int*)(buck + NE);
    ushort* agg  = (ushort*)(csr + NE);
    // d_out: first half = xb (bf16 x copy), second half = t1
    uint* xb     = (uint*)d_out;
    ushort* t1   = (ushort*)d_out + (size_t)NN * DD;
    ushort* t2   = agg;
    float* outp  = (float*)d_out;

    int gblk = (NN + 63) / 64;
    hipMemsetAsync(d_ws, 0, (16 + 512 + 3136) * sizeof(int), stream);
    k_mega<<<NB, 256, 0, stream>>>(x, xb, ei, ghistP, cb, gcurP, buck, csr, rowp,
                                   W1, W2, W3, Wb1, Wb2, Wb3, bar);
    k_gather<<<(NN + 3) / 4, 256, 0, stream>>>(xb, rowp, csr, agg);
    k_gemm<1><<<gblk, 256, 0, stream>>>(agg, Wb1, b1, nullptr, nullptr, nullptr, t1, stats);
    k_gemm<2><<<gblk, 256, 0, stream>>>(t1, Wb2, b2, stats, g1, be1, t2, stats + 256);
    k_gemm<3><<<gblk, 256, 0, stream>>>(t2, Wb3, nullptr, stats + 256, g2, be2, outp, nullptr);
}